// Round 7
// baseline (864.816 us; speedup 1.0000x reference)
//
#include <hip/hip_runtime.h>

// FeatureDecoder: 4x (Linear -> BN(batch stats) -> ReLU -> Linear) with gathers.
// R9: cross-block overlap. R8 proved more waves in ONE barrier group don't help
// (occupancy 20->40%, dur unchanged): the invariant since R4 is 1 block/CU
// (LDS >= 131KB) -> whole-CU barrier lockstep. m97's 874TF ran at ~3 blocks/CU
// (m114: cross-block MFMA+VALU co-schedule is the pipelining). New geometry:
// 128x128 tile, BK=64, 512 thr / 8 waves (2Mx4N, per-wave 64x32, acc 32 AGPR),
// LDS 72KB (A/B dbuf 64KB + ss 8KB, epilogue overlay) -> 2 independent
// blocks/CU; launch_bounds(512,4) caps 128 VGPR (16 waves/CU). Simple 1-ahead
// dbuf loop: stage(t+1) -> compute(t) -> VMCNT(0)+BAR; drain stalls hidden by
// the other block. AFFINE: rA loads before compute, AFFW after (latency under
// MFMA). T2 swizzle (involution verified) + T5 setprio + XCD swizzle kept.

typedef unsigned short u16;
typedef __attribute__((ext_vector_type(8))) short bf16x8;
typedef __attribute__((ext_vector_type(4))) float f32x4;

#define UNROLL _Pragma("unroll")
#define EPW 136  // epilogue LDS row stride (u16): 128+8

__device__ __forceinline__ float b2f(u16 u) {
    union { unsigned int i; float f; } v; v.i = ((unsigned int)u) << 16; return v.f;
}
__device__ __forceinline__ u16 f2b(float f) {
    union { float f; unsigned int i; } v; v.f = f;
    unsigned int r = v.i + 0x7FFFu + ((v.i >> 16) & 1u);
    return (u16)(r >> 16);
}

__device__ __forceinline__ void gld_lds16(const u16* g, u16* l) {
    __builtin_amdgcn_global_load_lds(
        (const __attribute__((address_space(1))) unsigned int*)g,
        (__attribute__((address_space(3))) unsigned int*)l,
        16, 0, 0);
}

#define VMCNT(n) asm volatile("s_waitcnt vmcnt(" #n ")" ::: "memory")
#define LGKM0    asm volatile("s_waitcnt lgkmcnt(0)" ::: "memory")
#define BAR()    do{ asm volatile("" ::: "memory"); \
                     __builtin_amdgcn_s_barrier(); \
                     asm volatile("" ::: "memory"); }while(0)

union SMem {
    struct { u16 a[2][8192]; u16 b[2][8192]; float ss[2048]; } st;  // 73728 B
    u16 ep[128 * EPW];                                               // 34816 B
};

// ---------------- GEMM: C(MxN) = A(MxK bf16) @ BT(NxK bf16)^T ----------------
// Tile 128x128, BK=64, 8 waves (wm=w>>2 in {0,1}, wn=w&3). Per-wave out 64x32.
template <bool AFFINE_A, bool STATS, bool OUT_F32, bool GATHER>
__global__ __launch_bounds__(512, 4) void gemm_bn(
    const u16* __restrict__ A, const u16* __restrict__ BT, void* __restrict__ Cout,
    const float* __restrict__ scale, const float* __restrict__ shift,
    const float* __restrict__ bias,
    float* __restrict__ psum, float* __restrict__ psumsq,
    const u16* __restrict__ Xg, const int* __restrict__ pool,
    int nfShift, int Nc, int Chalf,
    int N, int K)
{
    __shared__ __align__(16) SMem sm;

    const int tid  = threadIdx.x;
    const int w    = tid >> 6;        // 0..7
    const int lane = tid & 63;
    const int wm   = w >> 2, wn = w & 3;
    const int l15  = lane & 15;
    const int xorv = (lane & 7) << 3;                  // read-side swizzle
    const int swz8 = ((lane & 7) ^ (lane >> 3)) << 3;  // staging source swizzle

    // XCD-aware bijective swizzle (all grids %8==0, gridDim.x power of two).
    int bm, bn;
    {
        const int nbn  = (int)gridDim.x;
        const int nwg  = nbn * (int)gridDim.y;
        const int flat = (int)(blockIdx.y * gridDim.x + blockIdx.x);
        const int wg   = (flat & 7) * (nwg >> 3) + (flat >> 3);
        const int lb   = 31 - __builtin_clz(nbn);
        bn = wg & (nbn - 1);
        bm = wg >> lb;
    }

    // ---- staging units: 2 A-units + 2 B-units per wave (8 rows each) ----
    const u16* aS[2]; const u16* xS[2]; const u16* bS[2];
    int dA[2], dB[2], wIdx[2];
    UNROLL for (int u = 0; u < 2; u++) {
        const int trb = w * 16 + u * 8;        // wave-uniform 8-row chunk base
        const int tr  = trb + (lane >> 3);
        dA[u] = trb * 64;
        dB[u] = trb * 64;
        const int rowG = bm * 128 + tr;
        if constexpr (GATHER) {
            const int b = rowG >> nfShift;
            const int p = pool[rowG];
            aS[u] = A  + (size_t)rowG * Chalf + swz8;
            xS[u] = Xg + ((size_t)b * Nc + p) * Chalf + swz8;
        } else if constexpr (AFFINE_A) {
            aS[u] = A + (size_t)rowG * K + ((lane & 7) << 3);  // linear src
            wIdx[u] = tr * 64 + swz8;                          // swizzled dst
        } else {
            aS[u] = A + (size_t)rowG * K + swz8;
        }
        bS[u] = BT + (size_t)(bn * 128 + tr) * K + swz8;
    }

    f32x4 acc[4][2];
    const f32x4 zero = {0.f, 0.f, 0.f, 0.f};
    UNROLL for (int i = 0; i < 4; i++)
    UNROLL for (int j = 0; j < 2; j++) acc[i][j] = zero;
    uint4 rA[2];   // AFFINE in-flight A regs (DCE'd otherwise)

#define GLD_B(u, BASE, KOF) gld_lds16(bS[u] + (KOF), (BASE) + dB[u])

#define ISSUE_A(u, BASE, KOF) do{ \
    if constexpr (GATHER) { \
        const u16* s_ = ((KOF) < Chalf) ? (aS[u] + (KOF)) : (xS[u] + ((KOF) - Chalf)); \
        gld_lds16(s_, (BASE) + dA[u]); \
    } else { \
        gld_lds16(aS[u] + (KOF), (BASE) + dA[u]); \
    } }while(0)

#define LOAD_RA(u, KOF) do{ rA[u] = *(const uint4*)(aS[u] + (KOF)); }while(0)

#define AFFW(u, BASE, KOF) do{ if constexpr (AFFINE_A) { \
    const int kb_ = (KOF) + ((lane & 7) << 3); \
    const float4 sc0_ = *(const float4*)&sm.st.ss[kb_]; \
    const float4 sc1_ = *(const float4*)&sm.st.ss[kb_ + 4]; \
    const float4 sh0_ = *(const float4*)&sm.st.ss[1024 + kb_]; \
    const float4 sh1_ = *(const float4*)&sm.st.ss[1024 + kb_ + 4]; \
    union { uint4 u4; u16 s[8]; } r_, o_; r_.u4 = rA[u]; \
    o_.s[0] = f2b(fmaxf(b2f(r_.s[0]) * sc0_.x + sh0_.x, 0.f)); \
    o_.s[1] = f2b(fmaxf(b2f(r_.s[1]) * sc0_.y + sh0_.y, 0.f)); \
    o_.s[2] = f2b(fmaxf(b2f(r_.s[2]) * sc0_.z + sh0_.z, 0.f)); \
    o_.s[3] = f2b(fmaxf(b2f(r_.s[3]) * sc0_.w + sh0_.w, 0.f)); \
    o_.s[4] = f2b(fmaxf(b2f(r_.s[4]) * sc1_.x + sh1_.x, 0.f)); \
    o_.s[5] = f2b(fmaxf(b2f(r_.s[5]) * sc1_.y + sh1_.y, 0.f)); \
    o_.s[6] = f2b(fmaxf(b2f(r_.s[6]) * sc1_.z + sh1_.z, 0.f)); \
    o_.s[7] = f2b(fmaxf(b2f(r_.s[7]) * sc1_.w + sh1_.w, 0.f)); \
    *(uint4*)&((BASE))[wIdx[u]] = o_.u4; } }while(0)

#define COMPUTE_TILE(aB, bB) do{ \
    UNROLL for (int ks = 0; ks < 2; ks++) { \
        const int kS_ = (ks * 32 + ((lane >> 4) << 3)) ^ xorv; \
        bf16x8 afr[4], bfr[2]; \
        UNROLL for (int i_ = 0; i_ < 4; i_++) \
            afr[i_] = *(const bf16x8*)&(aB)[(wm * 64 + i_ * 16 + l15) * 64 + kS_]; \
        UNROLL for (int j_ = 0; j_ < 2; j_++) \
            bfr[j_] = *(const bf16x8*)&(bB)[(wn * 32 + j_ * 16 + l15) * 64 + kS_]; \
        __builtin_amdgcn_s_setprio(1); \
        UNROLL for (int i_ = 0; i_ < 4; i_++) \
        UNROLL for (int j_ = 0; j_ < 2; j_++) \
            acc[i_][j_] = __builtin_amdgcn_mfma_f32_16x16x32_bf16( \
                afr[i_], bfr[j_], acc[i_][j_], 0, 0, 0); \
        __builtin_amdgcn_s_setprio(0); \
    } }while(0)

    const int nkt = K >> 6;   // >= 8

    // ---- prologue: stage tile 0 into buf 0 ----
    if constexpr (AFFINE_A) {
        for (int i = tid; i < K; i += 512) {
            sm.st.ss[i] = scale[i]; sm.st.ss[1024 + i] = shift[i];
        }
        LOAD_RA(0, 0); LOAD_RA(1, 0);
        GLD_B(0, &sm.st.b[0][0], 0); GLD_B(1, &sm.st.b[0][0], 0);
        LGKM0; BAR();                      // ss visible to all waves
        AFFW(0, &sm.st.a[0][0], 0);        // compiler waits rA via vmcnt
        AFFW(1, &sm.st.a[0][0], 0);
        VMCNT(0); LGKM0; BAR();            // B(0) landed, A(0) writes visible
    } else {
        ISSUE_A(0, &sm.st.a[0][0], 0); ISSUE_A(1, &sm.st.a[0][0], 0);
        GLD_B(0, &sm.st.b[0][0], 0);   GLD_B(1, &sm.st.b[0][0], 0);
        VMCNT(0); BAR();
    }

    // ---- main loop: compute tile t, stage tile t+1 into other buffer ----
    for (int t = 0; t < nkt; ++t) {
        const int cb = t & 1, nb = cb ^ 1;
        const int kofN = (t + 1) << 6;
        u16* aC = &sm.st.a[cb][0]; u16* bC = &sm.st.b[cb][0];
        u16* aN = &sm.st.a[nb][0]; u16* bN = &sm.st.b[nb][0];
        const bool more = (t + 1 < nkt);
        if (more) {
            if constexpr (AFFINE_A) {
                LOAD_RA(0, kofN); LOAD_RA(1, kofN);   // issue; consumed post-compute
                GLD_B(0, bN, kofN); GLD_B(1, bN, kofN);
            } else {
                ISSUE_A(0, aN, kofN); ISSUE_A(1, aN, kofN);
                GLD_B(0, bN, kofN); GLD_B(1, bN, kofN);
            }
        }
        COMPUTE_TILE(aC, bC);
        if (more) {
            if constexpr (AFFINE_A) { AFFW(0, aN, kofN); AFFW(1, aN, kofN); }
            VMCNT(0);
        }
        LGKM0; BAR();
    }

    // ---- epilogue: C/D layout col=lane&15, row=(lane>>4)*4+reg ----
    const int cl = l15, quad = lane >> 4;
    if constexpr (OUT_F32) {
        UNROLL for (int j = 0; j < 2; j++) {
            const int col = bn * 128 + wn * 32 + j * 16 + cl;
            const float bcol = bias[col];
            UNROLL for (int i = 0; i < 4; i++) {
                const int r0 = bm * 128 + wm * 64 + i * 16 + quad * 4;
                UNROLL for (int r = 0; r < 4; r++)
                    ((float*)Cout)[(size_t)(r0 + r) * N + col] = acc[i][j][r] + bcol;
            }
        }
    } else {
        UNROLL for (int j = 0; j < 2; j++) {
            const int colL = wn * 32 + j * 16 + cl;
            const int col = bn * 128 + colL;
            float bcol = 0.f;
            if constexpr (!STATS) bcol = bias[col];
            float s = 0.f, ss2 = 0.f;
            UNROLL for (int i = 0; i < 4; i++) {
                const int rL0 = wm * 64 + i * 16 + quad * 4;
                UNROLL for (int r = 0; r < 4; r++) {
                    const float v = acc[i][j][r];
                    if constexpr (STATS) { s += v; ss2 += v * v; }
                    sm.ep[(rL0 + r) * EPW + colL] = f2b(v + bcol);
                }
            }
            if constexpr (STATS) {
                s   += __shfl_xor(s, 16);   s   += __shfl_xor(s, 32);
                ss2 += __shfl_xor(ss2, 16); ss2 += __shfl_xor(ss2, 32);
                if (quad == 0) { atomicAdd(&psum[col], s); atomicAdd(&psumsq[col], ss2); }
            }
        }
        __syncthreads();
        u16* Cb = (u16*)Cout;
        UNROLL for (int it = 0; it < 4; it++) {
            const int row = it * 32 + (tid >> 4);
            const int c8  = (tid & 15) * 8;
            const uint4 v = *(const uint4*)&sm.ep[row * EPW + c8];
            *(uint4*)(Cb + (size_t)(bm * 128 + row) * N + bn * 128 + c8) = v;
        }
    }
#undef GLD_B
#undef ISSUE_A
#undef LOAD_RA
#undef AFFW
#undef COMPUTE_TILE
}

// ---------------- W (KxN fp32) -> WT (NxK bf16), tiled transpose ----------------
__global__ void cvt_transpose_w(const float* __restrict__ W, u16* __restrict__ WT, int K, int N) {
    __shared__ float t[32][33];
    const int tx = threadIdx.x, ty = threadIdx.y;
    const int n0 = blockIdx.x * 32, k0 = blockIdx.y * 32;
#pragma unroll
    for (int r = 0; r < 4; r++)
        t[ty + r * 8][tx] = W[(size_t)(k0 + ty + r * 8) * N + n0 + tx];
    __syncthreads();
#pragma unroll
    for (int r = 0; r < 4; r++)
        WT[(size_t)(n0 + ty + r * 8) * K + k0 + tx] = f2b(t[tx][ty + r * 8]);
}

// ---------------- fp32 -> bf16 elementwise (8 elems/thread) ----------------
__global__ void cvt_f32_bf16(const float* __restrict__ x, u16* __restrict__ y, long n8) {
    const long t = (long)blockIdx.x * 256 + threadIdx.x;
    if (t >= n8) return;
    const float4 a = ((const float4*)x)[t * 2];
    const float4 b = ((const float4*)x)[t * 2 + 1];
    union { uint4 u; u16 s[8]; } o;
    o.s[0] = f2b(a.x); o.s[1] = f2b(a.y); o.s[2] = f2b(a.z); o.s[3] = f2b(a.w);
    o.s[4] = f2b(b.x); o.s[5] = f2b(b.y); o.s[6] = f2b(b.z); o.s[7] = f2b(b.w);
    ((uint4*)y)[t] = o.u;
}

// ---------------- per-channel BN scale/shift from sums ----------------
__global__ void bn_finalize(const float* __restrict__ sum, const float* __restrict__ sumsq,
                            const float* __restrict__ g, const float* __restrict__ be,
                            float* __restrict__ scale, float* __restrict__ shift,
                            int Cc, float invM) {
    const int c = blockIdx.x * 256 + threadIdx.x;
    if (c >= Cc) return;
    const float mu = sum[c] * invM;
    const float var = fmaf(sumsq[c], invM, -mu * mu);
    const float sc = g[c] * rsqrtf(var + 1e-5f);
    scale[c] = sc;
    shift[c] = fmaf(-mu, sc, be[c]);
}

extern "C" void kernel_launch(void* const* d_in, const int* in_sizes, int n_in,
                              void* d_out, int out_size, void* d_ws, size_t ws_size,
                              hipStream_t stream) {
    const float* f0     = (const float*)d_in[0];
    const float* f1     = (const float*)d_in[1];
    const float* f2     = (const float*)d_in[2];
    const float* up0_w1 = (const float*)d_in[3];
    const float* up0_g  = (const float*)d_in[5];
    const float* up0_be = (const float*)d_in[6];
    const float* up0_w2 = (const float*)d_in[7];
    const float* up0_b2 = (const float*)d_in[8];
    const float* up1_w1 = (const float*)d_in[9];
    const float* up1_g  = (const float*)d_in[11];
    const float* up1_be = (const float*)d_in[12];
    const float* up1_w2 = (const float*)d_in[13];
    const float* up1_b2 = (const float*)d_in[14];
    const float* sk0_w1 = (const float*)d_in[15];
    const float* sk0_g  = (const float*)d_in[17];
    const float* sk0_be = (const float*)d_in[18];
    const float* sk0_w2 = (const float*)d_in[19];
    const float* sk0_b2 = (const float*)d_in[20];
    const float* sk1_w1 = (const float*)d_in[21];
    const float* sk1_g  = (const float*)d_in[23];
    const float* sk1_be = (const float*)d_in[24];
    const float* sk1_w2 = (const float*)d_in[25];
    const float* sk1_b2 = (const float*)d_in[26];
    const int* pool0    = (const int*)d_in[27];
    const int* pool1    = (const int*)d_in[28];
    float* out = (float*)d_out;

    char* ws = (char*)d_ws;
    size_t off = 0;
    auto alloc = [&](size_t bytes) -> void* {
        void* p = ws + off;
        off += (bytes + 255) & ~(size_t)255;
        return p;
    };
    u16* w_up1_1 = (u16*)alloc((size_t)1024 * 1024 * 2);
    u16* w_up1_2 = (u16*)alloc((size_t)512 * 1024 * 2);
    u16* w_sk1_1 = (u16*)alloc((size_t)1024 * 1024 * 2);
    u16* w_sk1_2 = (u16*)alloc((size_t)512 * 1024 * 2);
    u16* w_up0_1 = (u16*)alloc((size_t)512 * 512 * 2);
    u16* w_up0_2 = (u16*)alloc((size_t)256 * 512 * 2);
    u16* w_sk0_1 = (u16*)alloc((size_t)512 * 512 * 2);
    u16* w_sk0_2 = (u16*)alloc((size_t)256 * 512 * 2);
    float* stats = (float*)alloc((size_t)4 * 4096 * 4);    // per MLP: sum|sumsq|scale|shift
    u16* Hbuf    = (u16*)alloc((size_t)131072 * 512 * 2);  // 134 MB
    u16* Xbuf    = (u16*)alloc((size_t)32768 * 512 * 2);   // 33 MB
    u16* f0b     = (u16*)alloc((size_t)4 * 32768 * 256 * 2); // 67 MB
    u16* f1b     = (u16*)alloc((size_t)4 * 8192 * 512 * 2);  // 33 MB
    u16* f2b_    = (u16*)alloc((size_t)4 * 2048 * 1024 * 2); // 17 MB

    const dim3 tb(32, 8);
    cvt_transpose_w<<<dim3(32, 32), tb, 0, stream>>>(up1_w1, w_up1_1, 1024, 1024);
    cvt_transpose_w<<<dim3(16, 32), tb, 0, stream>>>(up1_w2, w_up1_2, 1024, 512);
    cvt_transpose_w<<<dim3(32, 32), tb, 0, stream>>>(sk1_w1, w_sk1_1, 1024, 1024);
    cvt_transpose_w<<<dim3(16, 32), tb, 0, stream>>>(sk1_w2, w_sk1_2, 1024, 512);
    cvt_transpose_w<<<dim3(16, 16), tb, 0, stream>>>(up0_w1, w_up0_1, 512, 512);
    cvt_transpose_w<<<dim3(8, 16),  tb, 0, stream>>>(up0_w2, w_up0_2, 512, 256);
    cvt_transpose_w<<<dim3(16, 16), tb, 0, stream>>>(sk0_w1, w_sk0_1, 512, 512);
    cvt_transpose_w<<<dim3(8, 16),  tb, 0, stream>>>(sk0_w2, w_sk0_2, 512, 256);

    hipMemsetAsync(stats, 0, (size_t)4 * 4096 * sizeof(float), stream);
    cvt_f32_bf16<<<4096,  256, 0, stream>>>(f2, f2b_, 8388608L / 8);
    cvt_f32_bf16<<<8192,  256, 0, stream>>>(f1, f1b, 16777216L / 8);
    cvt_f32_bf16<<<16384, 256, 0, stream>>>(f0, f0b, 33554432L / 8);

    float* st0 = stats;
    float* st1 = stats + 4096;
    float* st2 = stats + 8192;
    float* st3 = stats + 12288;

    // ---- up1: (8192x1024)@(1024x1024) -> BN -> ReLU -> @(1024x512) ----
    gemm_bn<false, true, false, false><<<dim3(8, 64), 512, 0, stream>>>(
        f2b_, w_up1_1, Hbuf, nullptr, nullptr, nullptr, st0, st0 + 1024,
        nullptr, nullptr, 0, 0, 0, 1024, 1024);
    bn_finalize<<<4, 256, 0, stream>>>(st0, st0 + 1024, up1_g, up1_be, st0 + 2048, st0 + 3072, 1024, 1.f / 8192.f);
    gemm_bn<true, false, false, false><<<dim3(4, 64), 512, 0, stream>>>(
        Hbuf, w_up1_2, Xbuf, st0 + 2048, st0 + 3072, up1_b2, nullptr, nullptr,
        nullptr, nullptr, 0, 0, 0, 512, 1024);

    // ---- skip1: concat[f1|gather(X,pool1)] (32768x1024) @ w -> BN -> ReLU -> @ w2 ----
    gemm_bn<false, true, false, true><<<dim3(8, 256), 512, 0, stream>>>(
        f1b, w_sk1_1, Hbuf, nullptr, nullptr, nullptr, st1, st1 + 1024,
        Xbuf, pool1, 13, 2048, 512, 1024, 1024);
    bn_finalize<<<4, 256, 0, stream>>>(st1, st1 + 1024, sk1_g, sk1_be, st1 + 2048, st1 + 3072, 1024, 1.f / 32768.f);
    gemm_bn<true, false, false, false><<<dim3(4, 256), 512, 0, stream>>>(
        Hbuf, w_sk1_2, Xbuf, st1 + 2048, st1 + 3072, sk1_b2, nullptr, nullptr,
        nullptr, nullptr, 0, 0, 0, 512, 1024);

    // ---- up0: (32768x512)@(512x512) -> BN -> ReLU -> @(512x256) ----
    gemm_bn<false, true, false, false><<<dim3(4, 256), 512, 0, stream>>>(
        Xbuf, w_up0_1, Hbuf, nullptr, nullptr, nullptr, st2, st2 + 1024,
        nullptr, nullptr, 0, 0, 0, 512, 512);
    bn_finalize<<<2, 256, 0, stream>>>(st2, st2 + 1024, up0_g, up0_be, st2 + 2048, st2 + 3072, 512, 1.f / 32768.f);
    gemm_bn<true, false, false, false><<<dim3(2, 256), 512, 0, stream>>>(
        Hbuf, w_up0_2, Xbuf, st2 + 2048, st2 + 3072, up0_b2, nullptr, nullptr,
        nullptr, nullptr, 0, 0, 0, 256, 512);

    // ---- skip0: concat[f0|gather(X,pool0)] (131072x512) @ w -> BN -> ReLU -> @ w2 -> fp32 ----
    gemm_bn<false, true, false, true><<<dim3(4, 1024), 512, 0, stream>>>(
        f0b, w_sk0_1, Hbuf, nullptr, nullptr, nullptr, st3, st3 + 1024,
        Xbuf, pool0, 15, 8192, 256, 512, 512);
    bn_finalize<<<2, 256, 0, stream>>>(st3, st3 + 1024, sk0_g, sk0_be, st3 + 2048, st3 + 3072, 512, 1.f / 131072.f);
    gemm_bn<true, false, true, false><<<dim3(2, 1024), 512, 0, stream>>>(
        Hbuf, w_sk0_2, out, st3 + 2048, st3 + 3072, sk0_b2, nullptr, nullptr,
        nullptr, nullptr, 0, 0, 0, 256, 512);
}

// Round 9
// 802.403 us; speedup vs baseline: 1.0778x; 1.0778x over previous
//
#include <hip/hip_runtime.h>

// FeatureDecoder: 4x (Linear -> BN(batch stats) -> ReLU -> Linear) with gathers.
// R11 = R10 with the FP32A swizzle bug fixed. R10 loaded the fp32 A source at
// the SWIZZLED offset and wrote LDS at the swizzled wIdx -> the two XORs
// cancel -> LDS in identity layout, but reads always unswizzle -> wrong data
// on 7/8 rows. Fix (one line): fp32 reg-staged source uses the LINEAR per-lane
// offset ((lane&7)<<3), matching the proven AFFW pattern (linear src, swizzled
// ds_write). Structure otherwise identical to R9's passing GEMM (128x128/BK64/
// 8 waves/2 blocks-CU, T2 swizzle, T5 setprio, XCD swizzle, VMCNT(0) dbuf
// loop) + cvt fusion (3 cvt_f32_bf16 kernels deleted; GEMM1s read f0/f1/f2 as
// fp32, converting during A-staging; GATHER splits per K-tile at Chalf).

typedef unsigned short u16;
typedef __attribute__((ext_vector_type(8))) short bf16x8;
typedef __attribute__((ext_vector_type(4))) float f32x4;

#define UNROLL _Pragma("unroll")
#define EPW 136  // epilogue LDS row stride (u16): 128+8

__device__ __forceinline__ float b2f(u16 u) {
    union { unsigned int i; float f; } v; v.i = ((unsigned int)u) << 16; return v.f;
}
__device__ __forceinline__ u16 f2b(float f) {
    union { float f; unsigned int i; } v; v.f = f;
    unsigned int r = v.i + 0x7FFFu + ((v.i >> 16) & 1u);
    return (u16)(r >> 16);
}

__device__ __forceinline__ void gld_lds16(const u16* g, u16* l) {
    __builtin_amdgcn_global_load_lds(
        (const __attribute__((address_space(1))) unsigned int*)g,
        (__attribute__((address_space(3))) unsigned int*)l,
        16, 0, 0);
}

#define VMCNT(n) asm volatile("s_waitcnt vmcnt(" #n ")" ::: "memory")
#define LGKM0    asm volatile("s_waitcnt lgkmcnt(0)" ::: "memory")
#define BAR()    do{ asm volatile("" ::: "memory"); \
                     __builtin_amdgcn_s_barrier(); \
                     asm volatile("" ::: "memory"); }while(0)

union SMem {
    struct { u16 a[2][8192]; u16 b[2][8192]; float ss[2048]; } st;  // 73728 B
    u16 ep[128 * EPW];                                               // 34816 B
};

// ---------------- GEMM: C(MxN) = A(MxK) @ BT(NxK bf16)^T ----------------
// Tile 128x128, BK=64, 8 waves (wm=w>>2 in {0,1}, wn=w&3). Per-wave out 64x32.
// FP32A: A is fp32, converted to bf16 during staging (fused cvt).
template <bool AFFINE_A, bool STATS, bool OUT_F32, bool GATHER, bool FP32A>
__global__ __launch_bounds__(512, 4) void gemm_bn(
    const void* __restrict__ Araw, const u16* __restrict__ BT, void* __restrict__ Cout,
    const float* __restrict__ scale, const float* __restrict__ shift,
    const float* __restrict__ bias,
    float* __restrict__ psum, float* __restrict__ psumsq,
    const u16* __restrict__ Xg, const int* __restrict__ pool,
    int nfShift, int Nc, int Chalf,
    int N, int K)
{
    __shared__ __align__(16) SMem sm;

    const u16*   Ab = (const u16*)Araw;
    const float* Af = (const float*)Araw;

    const int tid  = threadIdx.x;
    const int w    = tid >> 6;        // 0..7
    const int lane = tid & 63;
    const int wm   = w >> 2, wn = w & 3;
    const int l15  = lane & 15;
    const int xorv = (lane & 7) << 3;                  // read-side swizzle
    const int swz8 = ((lane & 7) ^ (lane >> 3)) << 3;  // staging chunk (elems)
    const int lin8 = (lane & 7) << 3;                  // linear per-lane chunk

    // XCD-aware bijective swizzle (all grids %8==0, gridDim.x power of two).
    int bm, bn;
    {
        const int nbn  = (int)gridDim.x;
        const int nwg  = nbn * (int)gridDim.y;
        const int flat = (int)(blockIdx.y * gridDim.x + blockIdx.x);
        const int wg   = (flat & 7) * (nwg >> 3) + (flat >> 3);
        const int lb   = 31 - __builtin_clz(nbn);
        bn = wg & (nbn - 1);
        bm = wg >> lb;
    }

    // ---- staging units: 2 A-units + 2 B-units per wave (8 rows each) ----
    const u16* aS[2]; const u16* xS[2]; const u16* bS[2]; const float* aF[2];
    int dA[2], dB[2], wIdx[2];
    UNROLL for (int u = 0; u < 2; u++) {
        const int trb = w * 16 + u * 8;        // wave-uniform 8-row chunk base
        const int tr  = trb + (lane >> 3);
        dA[u] = trb * 64;
        dB[u] = trb * 64;
        const int rowG = bm * 128 + tr;
        if constexpr (GATHER) {
            const int b = rowG >> nfShift;
            const int p = pool[rowG];
            xS[u] = Xg + ((size_t)b * Nc + p) * Chalf + swz8;    // gld_lds: pre-swz src
            if constexpr (FP32A) {
                aF[u]   = Af + (size_t)rowG * Chalf + lin8;      // reg path: LINEAR src
                wIdx[u] = tr * 64 + swz8;                        // swizzled ds_write
            } else {
                aS[u] = Ab + (size_t)rowG * Chalf + swz8;
            }
        } else if constexpr (FP32A) {
            aF[u]   = Af + (size_t)rowG * K + lin8;              // LINEAR src (bugfix)
            wIdx[u] = tr * 64 + swz8;
        } else if constexpr (AFFINE_A) {
            aS[u]   = Ab + (size_t)rowG * K + lin8;              // linear src
            wIdx[u] = tr * 64 + swz8;                            // swizzled dst
        } else {
            aS[u] = Ab + (size_t)rowG * K + swz8;
        }
        bS[u] = BT + (size_t)(bn * 128 + tr) * K + swz8;
    }

    f32x4 acc[4][2];
    const f32x4 zero = {0.f, 0.f, 0.f, 0.f};
    UNROLL for (int i = 0; i < 4; i++)
    UNROLL for (int j = 0; j < 2; j++) acc[i][j] = zero;
    uint4 rA[2];       // AFFINE in-flight A regs (DCE'd otherwise)
    uint4 rF[2][2];    // FP32A in-flight fp32 A regs (DCE'd otherwise)

#define GLD_B(u, BASE, KOF) gld_lds16(bS[u] + (KOF), (BASE) + dB[u])

#define ISSUE_A(u, BASE, KOF) do{ \
    if constexpr (GATHER) { \
        gld_lds16(xS[u] + ((KOF) - Chalf), (BASE) + dA[u]); \
    } else { \
        gld_lds16(aS[u] + (KOF), (BASE) + dA[u]); \
    } }while(0)

#define LOAD_RA(u, KOF) do{ rA[u] = *(const uint4*)(aS[u] + (KOF)); }while(0)

#define LOAD_RF(u, KOF) do{ \
    rF[u][0] = *(const uint4*)(aF[u] + (KOF)); \
    rF[u][1] = *(const uint4*)(aF[u] + (KOF) + 4); }while(0)

#define CVW(u, BASE) do{ \
    union { uint4 u4[2]; float f[8]; } r_; \
    r_.u4[0] = rF[u][0]; r_.u4[1] = rF[u][1]; \
    union { uint4 u4; u16 s[8]; } o_; \
    UNROLL for (int e_ = 0; e_ < 8; e_++) o_.s[e_] = f2b(r_.f[e_]); \
    *(uint4*)&((BASE))[wIdx[u]] = o_.u4; }while(0)

#define AFFW(u, BASE, KOF) do{ if constexpr (AFFINE_A) { \
    const int kb_ = (KOF) + lin8; \
    const float4 sc0_ = *(const float4*)&sm.st.ss[kb_]; \
    const float4 sc1_ = *(const float4*)&sm.st.ss[kb_ + 4]; \
    const float4 sh0_ = *(const float4*)&sm.st.ss[1024 + kb_]; \
    const float4 sh1_ = *(const float4*)&sm.st.ss[1024 + kb_ + 4]; \
    union { uint4 u4; u16 s[8]; } r_, o_; r_.u4 = rA[u]; \
    o_.s[0] = f2b(fmaxf(b2f(r_.s[0]) * sc0_.x + sh0_.x, 0.f)); \
    o_.s[1] = f2b(fmaxf(b2f(r_.s[1]) * sc0_.y + sh0_.y, 0.f)); \
    o_.s[2] = f2b(fmaxf(b2f(r_.s[2]) * sc0_.z + sh0_.z, 0.f)); \
    o_.s[3] = f2b(fmaxf(b2f(r_.s[3]) * sc0_.w + sh0_.w, 0.f)); \
    o_.s[4] = f2b(fmaxf(b2f(r_.s[4]) * sc1_.x + sh1_.x, 0.f)); \
    o_.s[5] = f2b(fmaxf(b2f(r_.s[5]) * sc1_.y + sh1_.y, 0.f)); \
    o_.s[6] = f2b(fmaxf(b2f(r_.s[6]) * sc1_.z + sh1_.z, 0.f)); \
    o_.s[7] = f2b(fmaxf(b2f(r_.s[7]) * sc1_.w + sh1_.w, 0.f)); \
    *(uint4*)&((BASE))[wIdx[u]] = o_.u4; } }while(0)

#define COMPUTE_TILE(aB, bB) do{ \
    UNROLL for (int ks = 0; ks < 2; ks++) { \
        const int kS_ = (ks * 32 + ((lane >> 4) << 3)) ^ xorv; \
        bf16x8 afr[4], bfr[2]; \
        UNROLL for (int i_ = 0; i_ < 4; i_++) \
            afr[i_] = *(const bf16x8*)&(aB)[(wm * 64 + i_ * 16 + l15) * 64 + kS_]; \
        UNROLL for (int j_ = 0; j_ < 2; j_++) \
            bfr[j_] = *(const bf16x8*)&(bB)[(wn * 32 + j_ * 16 + l15) * 64 + kS_]; \
        __builtin_amdgcn_s_setprio(1); \
        UNROLL for (int i_ = 0; i_ < 4; i_++) \
        UNROLL for (int j_ = 0; j_ < 2; j_++) \
            acc[i_][j_] = __builtin_amdgcn_mfma_f32_16x16x32_bf16( \
                afr[i_], bfr[j_], acc[i_][j_], 0, 0, 0); \
        __builtin_amdgcn_s_setprio(0); \
    } }while(0)

    const int nkt = K >> 6;   // >= 8

    // ---- prologue: stage tile 0 into buf 0 ----
    if constexpr (AFFINE_A) {
        for (int i = tid; i < K; i += 512) {
            sm.st.ss[i] = scale[i]; sm.st.ss[1024 + i] = shift[i];
        }
        LOAD_RA(0, 0); LOAD_RA(1, 0);
        GLD_B(0, &sm.st.b[0][0], 0); GLD_B(1, &sm.st.b[0][0], 0);
        LGKM0; BAR();                      // ss visible to all waves
        AFFW(0, &sm.st.a[0][0], 0);        // compiler waits rA via vmcnt
        AFFW(1, &sm.st.a[0][0], 0);
        VMCNT(0); LGKM0; BAR();            // B(0) landed, A(0) writes visible
    } else if constexpr (FP32A) {
        LOAD_RF(0, 0); LOAD_RF(1, 0);      // tile 0 always fp32 (kof=0 < Chalf)
        GLD_B(0, &sm.st.b[0][0], 0); GLD_B(1, &sm.st.b[0][0], 0);
        CVW(0, &sm.st.a[0][0]);            // compiler waits rF via vmcnt
        CVW(1, &sm.st.a[0][0]);
        VMCNT(0); LGKM0; BAR();            // B(0) landed, A(0) writes visible
    } else {
        ISSUE_A(0, &sm.st.a[0][0], 0); ISSUE_A(1, &sm.st.a[0][0], 0);
        GLD_B(0, &sm.st.b[0][0], 0);   GLD_B(1, &sm.st.b[0][0], 0);
        VMCNT(0); BAR();
    }

    // ---- main loop: compute tile t, stage tile t+1 into other buffer ----
    for (int t = 0; t < nkt; ++t) {
        const int cb = t & 1, nb = cb ^ 1;
        const int kofN = (t + 1) << 6;
        u16* aC = &sm.st.a[cb][0]; u16* bC = &sm.st.b[cb][0];
        u16* aN = &sm.st.a[nb][0]; u16* bN = &sm.st.b[nb][0];
        const bool more = (t + 1 < nkt);
        bool fpN = false;
        if (more) {
            GLD_B(0, bN, kofN); GLD_B(1, bN, kofN);
            if constexpr (AFFINE_A) {
                LOAD_RA(0, kofN); LOAD_RA(1, kofN);   // consumed post-compute
            } else if constexpr (FP32A) {
                fpN = (!GATHER) || (kofN < Chalf);
                if (fpN) { LOAD_RF(0, kofN); LOAD_RF(1, kofN); }
                else     { ISSUE_A(0, aN, kofN); ISSUE_A(1, aN, kofN); }
            } else {
                ISSUE_A(0, aN, kofN); ISSUE_A(1, aN, kofN);
            }
        }
        COMPUTE_TILE(aC, bC);
        if (more) {
            if constexpr (AFFINE_A) { AFFW(0, aN, kofN); AFFW(1, aN, kofN); }
            else if constexpr (FP32A) { if (fpN) { CVW(0, aN); CVW(1, aN); } }
            VMCNT(0);
        }
        LGKM0; BAR();
    }

    // ---- epilogue: C/D layout col=lane&15, row=(lane>>4)*4+reg ----
    const int cl = l15, quad = lane >> 4;
    if constexpr (OUT_F32) {
        UNROLL for (int j = 0; j < 2; j++) {
            const int col = bn * 128 + wn * 32 + j * 16 + cl;
            const float bcol = bias[col];
            UNROLL for (int i = 0; i < 4; i++) {
                const int r0 = bm * 128 + wm * 64 + i * 16 + quad * 4;
                UNROLL for (int r = 0; r < 4; r++)
                    ((float*)Cout)[(size_t)(r0 + r) * N + col] = acc[i][j][r] + bcol;
            }
        }
    } else {
        UNROLL for (int j = 0; j < 2; j++) {
            const int colL = wn * 32 + j * 16 + cl;
            const int col = bn * 128 + colL;
            float bcol = 0.f;
            if constexpr (!STATS) bcol = bias[col];
            float s = 0.f, ss2 = 0.f;
            UNROLL for (int i = 0; i < 4; i++) {
                const int rL0 = wm * 64 + i * 16 + quad * 4;
                UNROLL for (int r = 0; r < 4; r++) {
                    const float v = acc[i][j][r];
                    if constexpr (STATS) { s += v; ss2 += v * v; }
                    sm.ep[(rL0 + r) * EPW + colL] = f2b(v + bcol);
                }
            }
            if constexpr (STATS) {
                s   += __shfl_xor(s, 16);   s   += __shfl_xor(s, 32);
                ss2 += __shfl_xor(ss2, 16); ss2 += __shfl_xor(ss2, 32);
                if (quad == 0) { atomicAdd(&psum[col], s); atomicAdd(&psumsq[col], ss2); }
            }
        }
        __syncthreads();
        u16* Cb = (u16*)Cout;
        UNROLL for (int it = 0; it < 4; it++) {
            const int row = it * 32 + (tid >> 4);
            const int c8  = (tid & 15) * 8;
            const uint4 v = *(const uint4*)&sm.ep[row * EPW + c8];
            *(uint4*)(Cb + (size_t)(bm * 128 + row) * N + bn * 128 + c8) = v;
        }
    }
#undef GLD_B
#undef ISSUE_A
#undef LOAD_RA
#undef LOAD_RF
#undef CVW
#undef AFFW
#undef COMPUTE_TILE
}

// ---------------- W (KxN fp32) -> WT (NxK bf16), tiled transpose ----------------
__global__ void cvt_transpose_w(const float* __restrict__ W, u16* __restrict__ WT, int K, int N) {
    __shared__ float t[32][33];
    const int tx = threadIdx.x, ty = threadIdx.y;
    const int n0 = blockIdx.x * 32, k0 = blockIdx.y * 32;
#pragma unroll
    for (int r = 0; r < 4; r++)
        t[ty + r * 8][tx] = W[(size_t)(k0 + ty + r * 8) * N + n0 + tx];
    __syncthreads();
#pragma unroll
    for (int r = 0; r < 4; r++)
        WT[(size_t)(n0 + ty + r * 8) * K + k0 + tx] = f2b(t[tx][ty + r * 8]);
}

// ---------------- per-channel BN scale/shift from sums ----------------
__global__ void bn_finalize(const float* __restrict__ sum, const float* __restrict__ sumsq,
                            const float* __restrict__ g, const float* __restrict__ be,
                            float* __restrict__ scale, float* __restrict__ shift,
                            int Cc, float invM) {
    const int c = blockIdx.x * 256 + threadIdx.x;
    if (c >= Cc) return;
    const float mu = sum[c] * invM;
    const float var = fmaf(sumsq[c], invM, -mu * mu);
    const float sc = g[c] * rsqrtf(var + 1e-5f);
    scale[c] = sc;
    shift[c] = fmaf(-mu, sc, be[c]);
}

extern "C" void kernel_launch(void* const* d_in, const int* in_sizes, int n_in,
                              void* d_out, int out_size, void* d_ws, size_t ws_size,
                              hipStream_t stream) {
    const float* f0     = (const float*)d_in[0];
    const float* f1     = (const float*)d_in[1];
    const float* f2     = (const float*)d_in[2];
    const float* up0_w1 = (const float*)d_in[3];
    const float* up0_g  = (const float*)d_in[5];
    const float* up0_be = (const float*)d_in[6];
    const float* up0_w2 = (const float*)d_in[7];
    const float* up0_b2 = (const float*)d_in[8];
    const float* up1_w1 = (const float*)d_in[9];
    const float* up1_g  = (const float*)d_in[11];
    const float* up1_be = (const float*)d_in[12];
    const float* up1_w2 = (const float*)d_in[13];
    const float* up1_b2 = (const float*)d_in[14];
    const float* sk0_w1 = (const float*)d_in[15];
    const float* sk0_g  = (const float*)d_in[17];
    const float* sk0_be = (const float*)d_in[18];
    const float* sk0_w2 = (const float*)d_in[19];
    const float* sk0_b2 = (const float*)d_in[20];
    const float* sk1_w1 = (const float*)d_in[21];
    const float* sk1_g  = (const float*)d_in[23];
    const float* sk1_be = (const float*)d_in[24];
    const float* sk1_w2 = (const float*)d_in[25];
    const float* sk1_b2 = (const float*)d_in[26];
    const int* pool0    = (const int*)d_in[27];
    const int* pool1    = (const int*)d_in[28];
    float* out = (float*)d_out;

    char* ws = (char*)d_ws;
    size_t off = 0;
    auto alloc = [&](size_t bytes) -> void* {
        void* p = ws + off;
        off += (bytes + 255) & ~(size_t)255;
        return p;
    };
    u16* w_up1_1 = (u16*)alloc((size_t)1024 * 1024 * 2);
    u16* w_up1_2 = (u16*)alloc((size_t)512 * 1024 * 2);
    u16* w_sk1_1 = (u16*)alloc((size_t)1024 * 1024 * 2);
    u16* w_sk1_2 = (u16*)alloc((size_t)512 * 1024 * 2);
    u16* w_up0_1 = (u16*)alloc((size_t)512 * 512 * 2);
    u16* w_up0_2 = (u16*)alloc((size_t)256 * 512 * 2);
    u16* w_sk0_1 = (u16*)alloc((size_t)512 * 512 * 2);
    u16* w_sk0_2 = (u16*)alloc((size_t)256 * 512 * 2);
    float* stats = (float*)alloc((size_t)4 * 4096 * 4);    // per MLP: sum|sumsq|scale|shift
    u16* Hbuf    = (u16*)alloc((size_t)131072 * 512 * 2);  // 134 MB
    u16* Xbuf    = (u16*)alloc((size_t)32768 * 512 * 2);   // 33 MB

    const dim3 tb(32, 8);
    cvt_transpose_w<<<dim3(32, 32), tb, 0, stream>>>(up1_w1, w_up1_1, 1024, 1024);
    cvt_transpose_w<<<dim3(16, 32), tb, 0, stream>>>(up1_w2, w_up1_2, 1024, 512);
    cvt_transpose_w<<<dim3(32, 32), tb, 0, stream>>>(sk1_w1, w_sk1_1, 1024, 1024);
    cvt_transpose_w<<<dim3(16, 32), tb, 0, stream>>>(sk1_w2, w_sk1_2, 1024, 512);
    cvt_transpose_w<<<dim3(16, 16), tb, 0, stream>>>(up0_w1, w_up0_1, 512, 512);
    cvt_transpose_w<<<dim3(8, 16),  tb, 0, stream>>>(up0_w2, w_up0_2, 512, 256);
    cvt_transpose_w<<<dim3(16, 16), tb, 0, stream>>>(sk0_w1, w_sk0_1, 512, 512);
    cvt_transpose_w<<<dim3(8, 16),  tb, 0, stream>>>(sk0_w2, w_sk0_2, 512, 256);

    hipMemsetAsync(stats, 0, (size_t)4 * 4096 * sizeof(float), stream);

    float* st0 = stats;
    float* st1 = stats + 4096;
    float* st2 = stats + 8192;
    float* st3 = stats + 12288;

    // ---- up1: (8192x1024 fp32)@(1024x1024) -> BN -> ReLU -> @(1024x512) ----
    gemm_bn<false, true, false, false, true><<<dim3(8, 64), 512, 0, stream>>>(
        f2, w_up1_1, Hbuf, nullptr, nullptr, nullptr, st0, st0 + 1024,
        nullptr, nullptr, 0, 0, 0, 1024, 1024);
    bn_finalize<<<4, 256, 0, stream>>>(st0, st0 + 1024, up1_g, up1_be, st0 + 2048, st0 + 3072, 1024, 1.f / 8192.f);
    gemm_bn<true, false, false, false, false><<<dim3(4, 64), 512, 0, stream>>>(
        Hbuf, w_up1_2, Xbuf, st0 + 2048, st0 + 3072, up1_b2, nullptr, nullptr,
        nullptr, nullptr, 0, 0, 0, 512, 1024);

    // ---- skip1: concat[f1 fp32|gather(X,pool1)] (32768x1024) @ w -> BN -> ReLU -> @ w2 ----
    gemm_bn<false, true, false, true, true><<<dim3(8, 256), 512, 0, stream>>>(
        f1, w_sk1_1, Hbuf, nullptr, nullptr, nullptr, st1, st1 + 1024,
        Xbuf, pool1, 13, 2048, 512, 1024, 1024);
    bn_finalize<<<4, 256, 0, stream>>>(st1, st1 + 1024, sk1_g, sk1_be, st1 + 2048, st1 + 3072, 1024, 1.f / 32768.f);
    gemm_bn<true, false, false, false, false><<<dim3(4, 256), 512, 0, stream>>>(
        Hbuf, w_sk1_2, Xbuf, st1 + 2048, st1 + 3072, sk1_b2, nullptr, nullptr,
        nullptr, nullptr, 0, 0, 0, 512, 1024);

    // ---- up0: (32768x512 bf16)@(512x512) -> BN -> ReLU -> @(512x256) ----
    gemm_bn<false, true, false, false, false><<<dim3(4, 256), 512, 0, stream>>>(
        Xbuf, w_up0_1, Hbuf, nullptr, nullptr, nullptr, st2, st2 + 1024,
        nullptr, nullptr, 0, 0, 0, 512, 512);
    bn_finalize<<<2, 256, 0, stream>>>(st2, st2 + 1024, up0_g, up0_be, st2 + 2048, st2 + 3072, 512, 1.f / 32768.f);
    gemm_bn<true, false, false, false, false><<<dim3(2, 256), 512, 0, stream>>>(
        Hbuf, w_up0_2, Xbuf, st2 + 2048, st2 + 3072, up0_b2, nullptr, nullptr,
        nullptr, nullptr, 0, 0, 0, 256, 512);

    // ---- skip0: concat[f0 fp32|gather(X,pool0)] (131072x512) @ w -> BN -> ReLU -> @ w2 -> fp32 ----
    gemm_bn<false, true, false, true, true><<<dim3(4, 1024), 512, 0, stream>>>(
        f0, w_sk0_1, Hbuf, nullptr, nullptr, nullptr, st3, st3 + 1024,
        Xbuf, pool0, 15, 8192, 256, 512, 512);
    bn_finalize<<<2, 256, 0, stream>>>(st3, st3 + 1024, sk0_g, sk0_be, st3 + 2048, st3 + 3072, 512, 1.f / 131072.f);
    gemm_bn<true, false, true, false, false><<<dim3(2, 1024), 512, 0, stream>>>(
        Hbuf, w_sk0_2, out, st3 + 2048, st3 + 3072, sk0_b2, nullptr, nullptr,
        nullptr, nullptr, 0, 0, 0, 256, 512);
}